// Round 3
// baseline (689.605 us; speedup 1.0000x reference)
//
#include <hip/hip_runtime.h>
#include <math.h>

#define N_RES 768
#define DISTO_BINS 64
#define LDDT_BINS 50
#define DISTO_BLOCKS 2048
#define LDDT_BLOCKS N_RES
#define EXP_GRID 64
#define NPAIRS (N_RES * N_RES)
#define NCHUNKS (NPAIRS / 4)          /* 147456 = 8192 waves * 18 */
#define CHUNKS_PER_WAVE 18
#define PAIRS_PER_BLOCK 288           /* 4 waves * 18 chunks * 4 pairs */

/* block order: [0,768) lddt | [768,832) exp | [832, 832+2048) disto
   small blocks first so they overlap the disto stream instead of tailing it */
#define TOTAL_BLOCKS (LDDT_BLOCKS + EXP_GRID + DISTO_BLOCKS)

/* ticket lives past all partial arrays (they end at 2944 floats) */
#define TICKET_BYTE_OFF 16384

// native vector type accepted by __builtin_nontemporal_load
typedef float f32x4 __attribute__((ext_vector_type(4)));

// 16-lane (DPP row) sum via row_ror rotations — pure VALU pipe.
#define ROW_ADD_ROR(v, N)                                                     \
    v += __int_as_float(__builtin_amdgcn_update_dpp(                          \
        0, __float_as_int(v), 0x120 | (N), 0xF, 0xF, false))

// ------------- Kernel A (mega): disto + lddt + exp + inline finalize -------
__global__ __launch_bounds__(256)
void mega_kernel(const f32x4* __restrict__ logits4,
                 const float* __restrict__ pb,          // (N,3)
                 const float* __restrict__ pbm,         // (N)
                 const float* __restrict__ pred37,      // (N,37,3)
                 const float* __restrict__ true37,      // (N,37,3)
                 const float* __restrict__ mask37,      // (N,37)
                 const float* __restrict__ lddt_logits, // (N,50)
                 const float* __restrict__ exl,         // (N,37)
                 const float* __restrict__ a37ex,       // (N,37)
                 float* __restrict__ partial,           // (DISTO_BLOCKS)
                 float* __restrict__ errm,              // (N)
                 float* __restrict__ expnum,            // (EXP_GRID)
                 float* __restrict__ expden,            // (EXP_GRID)
                 int* __restrict__ ticket,              // zeroed pre-launch
                 const float* __restrict__ resolution,  // (1,)
                 float* __restrict__ out) {
    __shared__ float r1[256], r2[256];
    __shared__ float swgt[PAIRS_PER_BLOCK];
    __shared__ int   sbin[PAIRS_PER_BLOCK];
    __shared__ int   isLast;
    const int tid  = threadIdx.x;
    const int nthr = blockDim.x;

    if (blockIdx.x >= LDDT_BLOCKS + EXP_GRID) {
        // ================= distogram partial sums =================
        const int db   = blockIdx.x - (LDDT_BLOCKS + EXP_GRID);
        const int lane = tid & 63;
        const int wid  = tid >> 6;
        const int q    = lane >> 4;    // pair-group 0..3 within wave
        const int gl   = lane & 15;    // lane within group
        const int gw   = db * 4 + wid;                  // wave id 0..8191
        const int base = gw * CHUNKS_PER_WAVE;          // contiguous 18 KB
        const int P0   = db * PAIRS_PER_BLOCK;

        // ---- inline pair meta (bins + weights) into LDS ----
        for (int idx = tid; idx < PAIRS_PER_BLOCK; idx += nthr) {
            int p = P0 + idx;
            int i = p / N_RES;
            int j = p - i * N_RES;
            float dx = pb[3 * i + 0] - pb[3 * j + 0];
            float dy = pb[3 * i + 1] - pb[3 * j + 1];
            float dz = pb[3 * i + 2] - pb[3 * j + 2];
            float d  = sqrtf(dx * dx + dy * dy + dz * dz);
            float t  = ceilf((d - 2.3125f) * 3.2f);   // 1/0.3125 = 3.2 exact
            sbin[idx] = (int)fminf(fmaxf(t, 0.f), 63.f);
            swgt[idx] = pbm[i] * pbm[j];
        }
        __syncthreads();

        const int mb = wid * 72 + q;   // per-lane LDS meta base

        float acc = 0.f;

#define DISTO_PROC(xv4, li)                                                   \
    {                                                                         \
        float e = __expf(xv4.x) + __expf(xv4.y) + __expf(xv4.z) +             \
                  __expf(xv4.w);                                              \
        ROW_ADD_ROR(e, 8);                                                    \
        ROW_ADD_ROR(e, 4);                                                    \
        ROW_ADD_ROR(e, 2);                                                    \
        ROW_ADD_ROR(e, 1);                                                    \
        int bin = sbin[li];                                                   \
        float w  = swgt[li];                                                  \
        float xs = (bin & 2) ? ((bin & 1) ? xv4.w : xv4.z)                    \
                             : ((bin & 1) ? xv4.y : xv4.x);                   \
        float lg = (gl == 0) ? w * __logf(e) : 0.f;                           \
        float bt = (gl == (bin >> 2)) ? w * xs : 0.f;                         \
        acc += lg - bt;                                                       \
    }

#pragma unroll
        for (int t3 = 0; t3 < 3; ++t3) {
            const int cb = base + t3 * 6;
            f32x4 x0 = __builtin_nontemporal_load(
                &logits4[(size_t)(cb + 0) * 64 + lane]);
            f32x4 x1 = __builtin_nontemporal_load(
                &logits4[(size_t)(cb + 1) * 64 + lane]);
            f32x4 x2 = __builtin_nontemporal_load(
                &logits4[(size_t)(cb + 2) * 64 + lane]);
            f32x4 x3 = __builtin_nontemporal_load(
                &logits4[(size_t)(cb + 3) * 64 + lane]);
            f32x4 x4 = __builtin_nontemporal_load(
                &logits4[(size_t)(cb + 4) * 64 + lane]);
            f32x4 x5 = __builtin_nontemporal_load(
                &logits4[(size_t)(cb + 5) * 64 + lane]);
            DISTO_PROC(x0, mb + 4 * (t3 * 6 + 0));
            DISTO_PROC(x1, mb + 4 * (t3 * 6 + 1));
            DISTO_PROC(x2, mb + 4 * (t3 * 6 + 2));
            DISTO_PROC(x3, mb + 4 * (t3 * 6 + 3));
            DISTO_PROC(x4, mb + 4 * (t3 * 6 + 4));
            DISTO_PROC(x5, mb + 4 * (t3 * 6 + 5));
        }
#undef DISTO_PROC

        // acc lives on all 64 lanes (log-term on gl==0, bin-terms on owners)
        acc += __shfl_xor(acc, 1, 64);
        acc += __shfl_xor(acc, 2, 64);
        acc += __shfl_xor(acc, 4, 64);
        acc += __shfl_xor(acc, 8, 64);
        acc += __shfl_xor(acc, 16, 64);
        acc += __shfl_xor(acc, 32, 64);
        if (lane == 0) r1[wid] = acc;
        __syncthreads();
        if (tid == 0)
            partial[db] = r1[0] + r1[1] + r1[2] + r1[3];

    } else if (blockIdx.x >= LDDT_BLOCKS) {
        // ================= exp-resolved partial sums =================
        const int b = blockIdx.x - LDDT_BLOCKS;
        const int gid = b * nthr + tid;
        const int stride = EXP_GRID * nthr;
        const int n = N_RES * 37;
        float num = 0.f, den = 0.f;
        for (int k = gid; k < n; k += stride) {
            float x  = exl[k];
            float m  = mask37[k];
            float ex = a37ex[k];
            float ax = fabsf(x);
            float sp = __logf(1.f + __expf(-ax));   // softplus(-|x|)
            float ls  = sp + fmaxf(-x, 0.f);        // -log_sigmoid(x)
            float lsn = sp + fmaxf(x, 0.f);         // -log_sigmoid(-x)
            float err = m * ls + (1.f - m) * lsn;
            num += err * ex;
            den += ex;
        }
        r1[tid] = num;
        r2[tid] = den;
        __syncthreads();
        for (int s = nthr >> 1; s > 0; s >>= 1) {
            if (tid < s) { r1[tid] += r1[tid + s]; r2[tid] += r2[tid + s]; }
            __syncthreads();
        }
        if (tid == 0) { expnum[b] = r1[0]; expden[b] = r2[0]; }

    } else {
        // ================= per-residue lddt + CE =================
        const int i = blockIdx.x;
        const float tix = true37[(i * 37 + 1) * 3 + 0];
        const float tiy = true37[(i * 37 + 1) * 3 + 1];
        const float tiz = true37[(i * 37 + 1) * 3 + 2];
        const float pix = pred37[(i * 37 + 1) * 3 + 0];
        const float piy = pred37[(i * 37 + 1) * 3 + 1];
        const float piz = pred37[(i * 37 + 1) * 3 + 2];
        const float mi  = mask37[i * 37 + 1];

        float scope_sum = 0.f, score_sum = 0.f;
        for (int j = tid; j < N_RES; j += nthr) {
            float mj  = mask37[j * 37 + 1];
            float dtx = tix - true37[(j * 37 + 1) * 3 + 0];
            float dty = tiy - true37[(j * 37 + 1) * 3 + 1];
            float dtz = tiz - true37[(j * 37 + 1) * 3 + 2];
            float dt  = sqrtf(1e-10f + dtx * dtx + dty * dty + dtz * dtz);
            float dpx = pix - pred37[(j * 37 + 1) * 3 + 0];
            float dpy = piy - pred37[(j * 37 + 1) * 3 + 1];
            float dpz = piz - pred37[(j * 37 + 1) * 3 + 2];
            float dp  = sqrtf(1e-10f + dpx * dpx + dpy * dpy + dpz * dpz);
            float scope = (dt < 15.f && j != i) ? (mi * mj) : 0.f;
            float l1 = fabsf(dt - dp);
            float sc = 0.25f * ((l1 < 0.5f ? 1.f : 0.f) + (l1 < 1.f ? 1.f : 0.f) +
                                (l1 < 2.f ? 1.f : 0.f) + (l1 < 4.f ? 1.f : 0.f));
            scope_sum += scope;
            score_sum += scope * sc;
        }

        r1[tid] = scope_sum;
        r2[tid] = score_sum;
        __syncthreads();
        for (int s = nthr >> 1; s > 0; s >>= 1) {
            if (tid < s) { r1[tid] += r1[tid + s]; r2[tid] += r2[tid + s]; }
            __syncthreads();
        }

        __shared__ int binS;
        if (tid == 0) {
            float lddt = (1e-10f + r2[0]) / (1e-10f + r1[0]);
            int bin = (int)floorf(lddt * (float)LDDT_BINS);
            binS = min(max(bin, 0), LDDT_BINS - 1);
        }
        __syncthreads();

        float e = (tid < LDDT_BINS) ? __expf(lddt_logits[i * LDDT_BINS + tid]) : 0.f;
        r1[tid] = e;
        __syncthreads();
        for (int s = nthr >> 1; s > 0; s >>= 1) {
            if (tid < s) r1[tid] += r1[tid + s];
            __syncthreads();
        }
        if (tid == 0) {
            float err = __logf(r1[0]) - lddt_logits[i * LDDT_BINS + binS];
            errm[i] = err * mi;
        }
    }

    // ================= last-block-done inline finalize =================
    __threadfence();                      // release our partials (device scope)
    if (tid == 0) {
        int old = atomicAdd(ticket, 1);   // device-scope RMW
        isLast = (old == TOTAL_BLOCKS - 1) ? 1 : 0;
    }
    __syncthreads();
    if (!isLast) return;
    __threadfence();                      // acquire all blocks' partials

    {
        double sd = 0.0, sm = 0.0, se = 0.0, smca = 0.0, num = 0.0, den = 0.0;
        for (int k = tid; k < DISTO_BLOCKS; k += nthr) sd += (double)partial[k];
        for (int k = tid; k < N_RES; k += nthr) {
            sm   += (double)pbm[k];
            se   += (double)errm[k];
            smca += (double)mask37[k * 37 + 1];
        }
        if (tid < EXP_GRID) { num = (double)expnum[tid]; den = (double)expden[tid]; }

        __shared__ double red[256];
        double vals[6] = {sd, sm, se, smca, num, den};
        double tot[6];
        for (int v = 0; v < 6; ++v) {
            red[tid] = vals[v];
            __syncthreads();
            for (int s = nthr >> 1; s > 0; s >>= 1) {
                if (tid < s) red[tid] += red[tid + s];
                __syncthreads();
            }
            tot[v] = red[0];
            __syncthreads();
        }

        if (tid == 0) {
            float res = resolution[0];
            double gate = (res >= 0.1f && res <= 3.0f) ? 1.0 : 0.0;
            double l_disto = tot[0] / (1e-6 + tot[1] * tot[1]);
            double l_plddt = tot[2] / (1e-10 + tot[3]) * gate;
            double l_exp   = tot[4] / (1e-8 + tot[5]) * gate;
            out[0] = (float)(0.3 * l_disto + 0.01 * l_plddt + 0.01 * l_exp);
        }
    }
}

extern "C" void kernel_launch(void* const* d_in, const int* in_sizes, int n_in,
                              void* d_out, int out_size, void* d_ws, size_t ws_size,
                              hipStream_t stream) {
    const float* disto       = (const float*)d_in[0];  // (1,768,768,64)
    const float* pb          = (const float*)d_in[1];  // (1,768,3)
    const float* pbm         = (const float*)d_in[2];  // (1,768)
    const float* lddt_logits = (const float*)d_in[3];  // (1,768,50)
    const float* pred        = (const float*)d_in[4];  // (1,768,37,3)
    const float* truep       = (const float*)d_in[5];  // (1,768,37,3)
    const float* am          = (const float*)d_in[6];  // (1,768,37)
    const float* exl         = (const float*)d_in[7];  // (1,768,37)
    const float* a37         = (const float*)d_in[8];  // (1,768,37)
    const float* resolution  = (const float*)d_in[9];  // (1,)
    float* out = (float*)d_out;

    float* ws      = (float*)d_ws;
    float* partial = ws;                         // DISTO_BLOCKS floats
    float* errm    = ws + DISTO_BLOCKS;          // N_RES
    float* expnum  = errm + N_RES;               // EXP_GRID
    float* expden  = expnum + EXP_GRID;          // EXP_GRID
    int*   ticket  = (int*)((char*)d_ws + TICKET_BYTE_OFF);

    // workspace is re-poisoned each iteration — ticket must start at 0
    hipMemsetAsync(ticket, 0, sizeof(int), stream);

    mega_kernel<<<TOTAL_BLOCKS, 256, 0, stream>>>(
        (const f32x4*)disto, pb, pbm,
        pred, truep, am, lddt_logits, exl, a37,
        partial, errm, expnum, expden, ticket, resolution, out);
}

// Round 4
// 227.443 us; speedup vs baseline: 3.0320x; 3.0320x over previous
//
#include <hip/hip_runtime.h>
#include <math.h>

#define N_RES 768
#define DISTO_BINS 64
#define LDDT_BINS 50
#define DISTO_BLOCKS 2048
#define LDDT_BLOCKS N_RES
#define EXP_GRID 64
#define NPAIRS (N_RES * N_RES)
#define NCHUNKS (NPAIRS / 4)          /* 147456 = 8192 waves * 18 */
#define CHUNKS_PER_WAVE 18
#define PAIRS_PER_BLOCK 288           /* 4 waves * 18 chunks * 4 pairs */

/* block order: [0,768) lddt | [768,832) exp | [832, 832+2048) disto
   small blocks first so they overlap the disto stream instead of tailing it */
#define TOTAL_BLOCKS (LDDT_BLOCKS + EXP_GRID + DISTO_BLOCKS)

// native vector type accepted by __builtin_nontemporal_load
typedef float f32x4 __attribute__((ext_vector_type(4)));

// 16-lane (DPP row) sum via row_ror rotations — pure VALU pipe.
#define ROW_ADD_ROR(v, N)                                                     \
    v += __int_as_float(__builtin_amdgcn_update_dpp(                          \
        0, __float_as_int(v), 0x120 | (N), 0xF, 0xF, false))

// ---------------- Kernel A (mega): disto stream + lddt + exp ---------------
__global__ __launch_bounds__(256)
void mega_kernel(const f32x4* __restrict__ logits4,
                 const float* __restrict__ pb,          // (N,3)
                 const float* __restrict__ pbm,         // (N)
                 const float* __restrict__ pred37,      // (N,37,3)
                 const float* __restrict__ true37,      // (N,37,3)
                 const float* __restrict__ mask37,      // (N,37)
                 const float* __restrict__ lddt_logits, // (N,50)
                 const float* __restrict__ exl,         // (N,37)
                 const float* __restrict__ a37ex,       // (N,37)
                 float* __restrict__ partial,           // (DISTO_BLOCKS)
                 float* __restrict__ errm,              // (N)
                 float* __restrict__ expnum,            // (EXP_GRID)
                 float* __restrict__ expden) {          // (EXP_GRID)
    __shared__ float r1[256], r2[256];
    __shared__ float swgt[PAIRS_PER_BLOCK];
    __shared__ int   sbin[PAIRS_PER_BLOCK];
    const int tid  = threadIdx.x;
    const int nthr = blockDim.x;

    if (blockIdx.x >= LDDT_BLOCKS + EXP_GRID) {
        // ================= distogram partial sums =================
        const int db   = blockIdx.x - (LDDT_BLOCKS + EXP_GRID);
        const int lane = tid & 63;
        const int wid  = tid >> 6;
        const int q    = lane >> 4;    // pair-group 0..3 within wave
        const int gl   = lane & 15;    // lane within group
        const int gw   = db * 4 + wid;                  // wave id 0..8191
        const int base = gw * CHUNKS_PER_WAVE;          // contiguous 18 KB
        const int P0   = db * PAIRS_PER_BLOCK;

        // ---- inline pair meta (bins + weights) into LDS ----
        for (int idx = tid; idx < PAIRS_PER_BLOCK; idx += nthr) {
            int p = P0 + idx;
            int i = p / N_RES;
            int j = p - i * N_RES;
            float dx = pb[3 * i + 0] - pb[3 * j + 0];
            float dy = pb[3 * i + 1] - pb[3 * j + 1];
            float dz = pb[3 * i + 2] - pb[3 * j + 2];
            float d  = sqrtf(dx * dx + dy * dy + dz * dz);
            float t  = ceilf((d - 2.3125f) * 3.2f);   // 1/0.3125 = 3.2 exact
            sbin[idx] = (int)fminf(fmaxf(t, 0.f), 63.f);
            swgt[idx] = pbm[i] * pbm[j];
        }
        __syncthreads();

        const int mb = wid * 72 + q;   // per-lane LDS meta base

        float acc = 0.f;

#define DISTO_PROC(xv4, li)                                                   \
    {                                                                         \
        float e = __expf(xv4.x) + __expf(xv4.y) + __expf(xv4.z) +             \
                  __expf(xv4.w);                                              \
        ROW_ADD_ROR(e, 8);                                                    \
        ROW_ADD_ROR(e, 4);                                                    \
        ROW_ADD_ROR(e, 2);                                                    \
        ROW_ADD_ROR(e, 1);                                                    \
        int bin = sbin[li];                                                   \
        float w  = swgt[li];                                                  \
        float xs = (bin & 2) ? ((bin & 1) ? xv4.w : xv4.z)                    \
                             : ((bin & 1) ? xv4.y : xv4.x);                   \
        float lg = (gl == 0) ? w * __logf(e) : 0.f;                           \
        float bt = (gl == (bin >> 2)) ? w * xs : 0.f;                         \
        acc += lg - bt;                                                       \
    }

#pragma unroll
        for (int t3 = 0; t3 < 3; ++t3) {
            const int cb = base + t3 * 6;
            f32x4 x0 = __builtin_nontemporal_load(
                &logits4[(size_t)(cb + 0) * 64 + lane]);
            f32x4 x1 = __builtin_nontemporal_load(
                &logits4[(size_t)(cb + 1) * 64 + lane]);
            f32x4 x2 = __builtin_nontemporal_load(
                &logits4[(size_t)(cb + 2) * 64 + lane]);
            f32x4 x3 = __builtin_nontemporal_load(
                &logits4[(size_t)(cb + 3) * 64 + lane]);
            f32x4 x4 = __builtin_nontemporal_load(
                &logits4[(size_t)(cb + 4) * 64 + lane]);
            f32x4 x5 = __builtin_nontemporal_load(
                &logits4[(size_t)(cb + 5) * 64 + lane]);
            DISTO_PROC(x0, mb + 4 * (t3 * 6 + 0));
            DISTO_PROC(x1, mb + 4 * (t3 * 6 + 1));
            DISTO_PROC(x2, mb + 4 * (t3 * 6 + 2));
            DISTO_PROC(x3, mb + 4 * (t3 * 6 + 3));
            DISTO_PROC(x4, mb + 4 * (t3 * 6 + 4));
            DISTO_PROC(x5, mb + 4 * (t3 * 6 + 5));
        }
#undef DISTO_PROC

        // acc lives on all 64 lanes (log-term on gl==0, bin-terms on owners)
        acc += __shfl_xor(acc, 1, 64);
        acc += __shfl_xor(acc, 2, 64);
        acc += __shfl_xor(acc, 4, 64);
        acc += __shfl_xor(acc, 8, 64);
        acc += __shfl_xor(acc, 16, 64);
        acc += __shfl_xor(acc, 32, 64);
        if (lane == 0) r1[wid] = acc;
        __syncthreads();
        if (tid == 0)
            partial[db] = r1[0] + r1[1] + r1[2] + r1[3];
        return;
    }

    if (blockIdx.x >= LDDT_BLOCKS) {
        // ================= exp-resolved partial sums =================
        const int b = blockIdx.x - LDDT_BLOCKS;
        const int gid = b * nthr + tid;
        const int stride = EXP_GRID * nthr;
        const int n = N_RES * 37;
        float num = 0.f, den = 0.f;
        for (int k = gid; k < n; k += stride) {
            float x  = exl[k];
            float m  = mask37[k];
            float ex = a37ex[k];
            float ax = fabsf(x);
            float sp = __logf(1.f + __expf(-ax));   // softplus(-|x|)
            float ls  = sp + fmaxf(-x, 0.f);        // -log_sigmoid(x)
            float lsn = sp + fmaxf(x, 0.f);         // -log_sigmoid(-x)
            float err = m * ls + (1.f - m) * lsn;
            num += err * ex;
            den += ex;
        }
        r1[tid] = num;
        r2[tid] = den;
        __syncthreads();
        for (int s = nthr >> 1; s > 0; s >>= 1) {
            if (tid < s) { r1[tid] += r1[tid + s]; r2[tid] += r2[tid + s]; }
            __syncthreads();
        }
        if (tid == 0) { expnum[b] = r1[0]; expden[b] = r2[0]; }
        return;
    }

    // ================= per-residue lddt + CE =================
    const int i = blockIdx.x;
    const float tix = true37[(i * 37 + 1) * 3 + 0];
    const float tiy = true37[(i * 37 + 1) * 3 + 1];
    const float tiz = true37[(i * 37 + 1) * 3 + 2];
    const float pix = pred37[(i * 37 + 1) * 3 + 0];
    const float piy = pred37[(i * 37 + 1) * 3 + 1];
    const float piz = pred37[(i * 37 + 1) * 3 + 2];
    const float mi  = mask37[i * 37 + 1];

    float scope_sum = 0.f, score_sum = 0.f;
    for (int j = tid; j < N_RES; j += nthr) {
        float mj  = mask37[j * 37 + 1];
        float dtx = tix - true37[(j * 37 + 1) * 3 + 0];
        float dty = tiy - true37[(j * 37 + 1) * 3 + 1];
        float dtz = tiz - true37[(j * 37 + 1) * 3 + 2];
        float dt  = sqrtf(1e-10f + dtx * dtx + dty * dty + dtz * dtz);
        float dpx = pix - pred37[(j * 37 + 1) * 3 + 0];
        float dpy = piy - pred37[(j * 37 + 1) * 3 + 1];
        float dpz = piz - pred37[(j * 37 + 1) * 3 + 2];
        float dp  = sqrtf(1e-10f + dpx * dpx + dpy * dpy + dpz * dpz);
        float scope = (dt < 15.f && j != i) ? (mi * mj) : 0.f;
        float l1 = fabsf(dt - dp);
        float sc = 0.25f * ((l1 < 0.5f ? 1.f : 0.f) + (l1 < 1.f ? 1.f : 0.f) +
                            (l1 < 2.f ? 1.f : 0.f) + (l1 < 4.f ? 1.f : 0.f));
        scope_sum += scope;
        score_sum += scope * sc;
    }

    r1[tid] = scope_sum;
    r2[tid] = score_sum;
    __syncthreads();
    for (int s = nthr >> 1; s > 0; s >>= 1) {
        if (tid < s) { r1[tid] += r1[tid + s]; r2[tid] += r2[tid + s]; }
        __syncthreads();
    }

    __shared__ int binS;
    if (tid == 0) {
        float lddt = (1e-10f + r2[0]) / (1e-10f + r1[0]);
        int bin = (int)floorf(lddt * (float)LDDT_BINS);
        binS = min(max(bin, 0), LDDT_BINS - 1);
    }
    __syncthreads();

    float e = (tid < LDDT_BINS) ? __expf(lddt_logits[i * LDDT_BINS + tid]) : 0.f;
    r1[tid] = e;
    __syncthreads();
    for (int s = nthr >> 1; s > 0; s >>= 1) {
        if (tid < s) r1[tid] += r1[tid + s];
        __syncthreads();
    }
    if (tid == 0) {
        float err = __logf(r1[0]) - lddt_logits[i * LDDT_BINS + binS];
        errm[i] = err * mi;
    }
}

// ---------------- Kernel C: final combine (small reductions only) --------
__global__ __launch_bounds__(256)
void finalize_kernel(const float* __restrict__ partial,  // (DISTO_BLOCKS)
                     const float* __restrict__ pbm,      // (N,)
                     const float* __restrict__ errm,     // (N,)
                     const float* __restrict__ mask37,   // (N,37)
                     const float* __restrict__ expnum,   // (EXP_GRID)
                     const float* __restrict__ expden,   // (EXP_GRID)
                     const float* __restrict__ resolution,
                     float* __restrict__ out) {
    const int tid = threadIdx.x;
    const int nthr = blockDim.x;

    double sd = 0.0, sm = 0.0, se = 0.0, smca = 0.0, num = 0.0, den = 0.0;
    for (int k = tid; k < DISTO_BLOCKS; k += nthr) sd += (double)partial[k];
    for (int k = tid; k < N_RES; k += nthr) {
        sm   += (double)pbm[k];
        se   += (double)errm[k];
        smca += (double)mask37[k * 37 + 1];
    }
    if (tid < EXP_GRID) { num = (double)expnum[tid]; den = (double)expden[tid]; }

    __shared__ double red[256];
    double vals[6] = {sd, sm, se, smca, num, den};
    double tot[6];
    for (int v = 0; v < 6; ++v) {
        red[tid] = vals[v];
        __syncthreads();
        for (int s = nthr >> 1; s > 0; s >>= 1) {
            if (tid < s) red[tid] += red[tid + s];
            __syncthreads();
        }
        tot[v] = red[0];
        __syncthreads();
    }

    if (tid == 0) {
        float res = resolution[0];
        double gate = (res >= 0.1f && res <= 3.0f) ? 1.0 : 0.0;
        double l_disto = tot[0] / (1e-6 + tot[1] * tot[1]);
        double l_plddt = tot[2] / (1e-10 + tot[3]) * gate;
        double l_exp   = tot[4] / (1e-8 + tot[5]) * gate;
        out[0] = (float)(0.3 * l_disto + 0.01 * l_plddt + 0.01 * l_exp);
    }
}

extern "C" void kernel_launch(void* const* d_in, const int* in_sizes, int n_in,
                              void* d_out, int out_size, void* d_ws, size_t ws_size,
                              hipStream_t stream) {
    const float* disto       = (const float*)d_in[0];  // (1,768,768,64)
    const float* pb          = (const float*)d_in[1];  // (1,768,3)
    const float* pbm         = (const float*)d_in[2];  // (1,768)
    const float* lddt_logits = (const float*)d_in[3];  // (1,768,50)
    const float* pred        = (const float*)d_in[4];  // (1,768,37,3)
    const float* truep       = (const float*)d_in[5];  // (1,768,37,3)
    const float* am          = (const float*)d_in[6];  // (1,768,37)
    const float* exl         = (const float*)d_in[7];  // (1,768,37)
    const float* a37         = (const float*)d_in[8];  // (1,768,37)
    const float* resolution  = (const float*)d_in[9];  // (1,)
    float* out = (float*)d_out;

    float* ws      = (float*)d_ws;
    float* partial = ws;                         // DISTO_BLOCKS floats
    float* errm    = ws + DISTO_BLOCKS;          // N_RES
    float* expnum  = errm + N_RES;               // EXP_GRID
    float* expden  = expnum + EXP_GRID;          // EXP_GRID

    mega_kernel<<<TOTAL_BLOCKS, 256, 0, stream>>>(
        (const f32x4*)disto, pb, pbm,
        pred, truep, am, lddt_logits, exl, a37,
        partial, errm, expnum, expden);
    finalize_kernel<<<1, 256, 0, stream>>>(partial, pbm, errm, am,
                                           expnum, expden, resolution, out);
}